// Round 5
// baseline (519.657 us; speedup 1.0000x reference)
//
#include <hip/hip_runtime.h>
#include <hip/hip_bf16.h>
#include <math.h>

#define WW     160
#define NBATCH 4
#define VOL    (160*160*160)      // 4,096,000
#define PLANE  (160*160)

#define C1f 0.0001f
#define C2f 0.0009f

#define RUN_H 16                  // h outputs per k_wh block
#define NROWS (RUN_H + 10)        // 26 rows staged
#define LDW   176                 // padded cols: [0..4]=0, [5..164]=data, [165..175]=0
#define RUN_D 20                  // d outputs per k_dssim block

struct Gw { float g[11]; };

__device__ __forceinline__ float bf2f(unsigned short u) {
    return __uint_as_float(((unsigned int)u) << 16);
}
__device__ __forceinline__ unsigned short f2bf(float f) {
    __hip_bfloat16 h = __float2bfloat16(f);
    return *reinterpret_cast<unsigned short*>(&h);
}

// ---------------- Pass A: W+H conv fused; one-shot LDS tile; bf16-packed output ----
// block 192 (3 waves; threads 0..159 compute, all 192 load)
// grid (160/RUN_H, d=160, batch=4) = 6400 blocks, single dispatch
__global__ __launch_bounds__(192) void k_wh(
    const float* __restrict__ x, const float* __restrict__ y,
    ushort4* __restrict__ B4, unsigned short* __restrict__ B1, Gw gw)
{
    __shared__ float2 tile[NROWS][LDW];    // 26*176*8 = 36.6 KB
    const int t  = threadIdx.x;
    const int h0 = blockIdx.x * RUN_H;
    const int d  = blockIdx.y;
    const int n  = blockIdx.z;

    const float* xb = x + (size_t)n * VOL + (size_t)d * PLANE;
    const float* yb = y + (size_t)n * VOL + (size_t)d * PLANE;

    // ---- fill tile: ~24 slots/thread, all loads independent ----
#pragma unroll 4
    for (int s = t; s < NROWS * LDW; s += 192) {
        int r = s / LDW, c = s - r * LDW;
        int h = h0 - 5 + r;
        int w = c - 5;
        float vx = 0.f, vy = 0.f;
        if (h >= 0 && h < 160 && w >= 0 && w < 160) {
            size_t idx = (size_t)h * WW + w;
            vx = xb[idx];
            vy = yb[idx];
        }
        tile[r][c] = make_float2(vx, vy);
    }
    __syncthreads();

    // ---- compute: pure LDS + VALU ----
    if (t < 160) {
        const int w = t;
        const size_t outbase = (size_t)n * VOL + (size_t)d * PLANE + w;
        float ring[5][11];
#pragma unroll
        for (int i = 0; i < NROWS; ++i) {
            float a0=0.f,a1=0.f,a2=0.f,a3=0.f,a4=0.f;
#pragma unroll
            for (int k = 0; k < 11; ++k) {
                float2 v = tile[i][w + k];     // input w-5+k
                float g = gw.g[k];
                a0 += g * v.x;
                a1 += g * v.y;
                a2 += g * (v.x * v.x);
                a3 += g * (v.y * v.y);
                a4 += g * (v.x * v.y);
            }
            ring[0][i%11]=a0; ring[1][i%11]=a1; ring[2][i%11]=a2;
            ring[3][i%11]=a3; ring[4][i%11]=a4;

            if (i >= 10) {
                const int j = i - 10;          // output row h0+j
                float o[5] = {0.f,0.f,0.f,0.f,0.f};
#pragma unroll
                for (int k = 0; k < 11; ++k) {
                    float g = gw.g[k];
#pragma unroll
                    for (int c = 0; c < 5; ++c)
                        o[c] += g * ring[c][(j + k) % 11];
                }
                size_t oi = outbase + (size_t)(h0 + j) * WW;
                ushort4 u4;
                u4.x = f2bf(o[0]); u4.y = f2bf(o[1]);
                u4.z = f2bf(o[2]); u4.w = f2bf(o[3]);
                B4[oi] = u4;
                B1[oi] = f2bf(o[4]);
            }
        }
    }
}

// ---------------- Pass B: D-conv + SSIM; packed bf16 loads, register prefetch ----
// block 256 (wave wi -> h = by*4+wi, lanes -> w chunk)
// grid (3, 40, 8*4) = 3840 blocks, single dispatch
__global__ __launch_bounds__(256, 4) void k_dssim(
    const ushort4* __restrict__ B4, const unsigned short* __restrict__ B1,
    double* __restrict__ accum, Gw gw)
{
    const int lane = threadIdx.x & 63;
    const int wi   = threadIdx.x >> 6;
    const int w    = blockIdx.x * 64 + lane;
    const int h    = blockIdx.y * 4 + wi;
    const int dseg = blockIdx.z & 7;
    const int n    = blockIdx.z >> 3;
    const int d0   = dseg * RUN_D;

    float lsum = 0.f;
    if (w < 160) {
        const size_t base = (size_t)n * VOL + (size_t)h * WW + w;
        float ring[5][11];
        ushort4 p4; unsigned short p1; bool pok;
        {   // prefetch i=0 (d = d0-5)
            int dd = d0 - 5;
            pok = (dd >= 0) && (dd < 160);
            size_t idx = base + (size_t)(pok ? dd : 0) * PLANE;
            p4 = B4[idx];
            p1 = B1[idx];
        }
#pragma unroll
        for (int i = 0; i < RUN_D + 10; ++i) {
            ushort4 q4 = p4; unsigned short q1 = p1; bool qok = pok;
            // issue next slice's 2 loads now; consumed next iteration
            if (i + 1 < RUN_D + 10) {
                int dd = d0 - 5 + i + 1;
                pok = (dd >= 0) && (dd < 160);
                size_t idx = base + (size_t)(pok ? dd : 0) * PLANE;
                p4 = B4[idx];
                p1 = B1[idx];
            }
            ring[0][i%11] = qok ? bf2f(q4.x) : 0.f;
            ring[1][i%11] = qok ? bf2f(q4.y) : 0.f;
            ring[2][i%11] = qok ? bf2f(q4.z) : 0.f;
            ring[3][i%11] = qok ? bf2f(q4.w) : 0.f;
            ring[4][i%11] = qok ? bf2f(q1)   : 0.f;

            if (i >= 10) {
                const int j = i - 10;
                float o[5] = {0.f,0.f,0.f,0.f,0.f};
#pragma unroll
                for (int k = 0; k < 11; ++k) {
                    float g = gw.g[k];
#pragma unroll
                    for (int c = 0; c < 5; ++c)
                        o[c] += g * ring[c][(j + k) % 11];
                }
                float mu1 = o[0], mu2 = o[1];
                float e11 = o[2], e22 = o[3], e12 = o[4];
                float m11 = mu1 * mu2;
                float num = (2.f * m11 + C1f) * (2.f * (e12 - m11) + C2f);
                float den = (mu1 * mu1 + mu2 * mu2 + C1f) *
                            ((e11 - mu1 * mu1) + (e22 - mu2 * mu2) + C2f);
                lsum += num / den;
            }
        }
    }
    // wave reduce then block reduce, one atomic per block
    __shared__ float wsum[4];
#pragma unroll
    for (int off = 32; off > 0; off >>= 1)
        lsum += __shfl_down(lsum, off, 64);
    if (lane == 0) wsum[wi] = lsum;
    __syncthreads();
    if (threadIdx.x == 0)
        atomicAdd(accum, (double)(wsum[0] + wsum[1] + wsum[2] + wsum[3]));
}

__global__ void k_final(const double* __restrict__ accum, float* __restrict__ out)
{
    out[0] = (float)(1.0 - accum[0] / ((double)NBATCH * (double)VOL));
}

extern "C" void kernel_launch(void* const* d_in, const int* in_sizes, int n_in,
                              void* d_out, int out_size, void* d_ws, size_t ws_size,
                              hipStream_t stream)
{
    const float* img1 = (const float*)d_in[0];
    const float* img2 = (const float*)d_in[1];
    float* out = (float*)d_out;

    char* ws = (char*)d_ws;
    ushort4* B4 = (ushort4*)ws;                                   // 4*VOL*8B  = 131.07 MB
    unsigned short* B1 = (unsigned short*)(ws + (size_t)NBATCH * VOL * 8);  // 32.77 MB
    double* accum = (double*)(ws + (size_t)NBATCH * VOL * 10);    // total 163.84 MB + 8

    Gw gw;
    {
        double gd[11], s = 0.0;
        for (int i = 0; i < 11; ++i) {
            double t = (double)(i - 5);
            gd[i] = exp(-(t * t) / (2.0 * 1.5 * 1.5));
            s += gd[i];
        }
        for (int i = 0; i < 11; ++i) gw.g[i] = (float)(gd[i] / s);
    }

    hipMemsetAsync(accum, 0, sizeof(double), stream);

    k_wh   <<<dim3(160 / RUN_H, 160, NBATCH), 192, 0, stream>>>(img1, img2, B4, B1, gw);
    k_dssim<<<dim3(3, 40, 8 * NBATCH), 256, 0, stream>>>(B4, B1, accum, gw);
    k_final<<<1, 1, 0, stream>>>(accum, out);
}

// Round 6
// 325.715 us; speedup vs baseline: 1.5954x; 1.5954x over previous
//
#include <hip/hip_runtime.h>
#include <hip/hip_bf16.h>
#include <math.h>

#define WW     160
#define NBATCH 4
#define VOL    (160*160*160)      // 4,096,000
#define PLANE  (160*160)

#define C1f 0.0001f
#define C2f 0.0009f

#define RUN_H 16                  // h outputs per k_wh block
#define NROWS (RUN_H + 10)        // 26 rows staged
#define LDW   176                 // padded cols: [0..4]=0, [5..164]=data, [165..175]=0
#define RUN_D 32                  // d outputs per k_dssim block (5 segments)

typedef float v2f __attribute__((ext_vector_type(2)));

struct Gw { float g[11]; };

__device__ __forceinline__ float bf2f(unsigned short u) {
    return __uint_as_float(((unsigned int)u) << 16);
}
__device__ __forceinline__ unsigned short f2bf(float f) {
    __hip_bfloat16 h = __float2bfloat16(f);   // RNE
    return *reinterpret_cast<unsigned short*>(&h);
}

// ---------------- Pass A: W+H conv fused; bf16x2-packed LDS tile ----------------
// block 192 (3 waves; threads 0..159 compute, all 192 load)
// grid (10, d=160, batch=4) = 6400 blocks
__global__ __launch_bounds__(192, 5) void k_wh(
    const float* __restrict__ x, const float* __restrict__ y,
    ushort4* __restrict__ B4, unsigned short* __restrict__ B1, Gw gw)
{
    __shared__ unsigned int tile[NROWS][LDW];   // 26*176*4 = 18.3 KB -> 8 blocks/CU (LDS)
    const int t  = threadIdx.x;
    const int h0 = blockIdx.x * RUN_H;
    const int d  = blockIdx.y;
    const int n  = blockIdx.z;

    const float* xb = x + (size_t)n * VOL + (size_t)d * PLANE;
    const float* yb = y + (size_t)n * VOL + (size_t)d * PLANE;

    // ---- fill tile: independent coalesced loads, pack bf16(y)<<16 | bf16(x) ----
#pragma unroll 4
    for (int s = t; s < NROWS * LDW; s += 192) {
        int r = s / LDW, c = s - r * LDW;
        int h = h0 - 5 + r;
        int w = c - 5;
        float vx = 0.f, vy = 0.f;
        if (h >= 0 && h < 160 && w >= 0 && w < 160) {
            size_t idx = (size_t)h * WW + w;
            vx = xb[idx];
            vy = yb[idx];
        }
        tile[r][c] = ((unsigned int)f2bf(vy) << 16) | (unsigned int)f2bf(vx);
    }
    __syncthreads();

    // ---- compute: LDS + packed-f32 VALU ----
    if (t < 160) {
        const int w = t;
        const size_t outbase = (size_t)n * VOL + (size_t)d * PLANE + w;
        v2f ring01[11], ring23[11];
        float ring4[11];
#pragma unroll
        for (int i = 0; i < NROWS; ++i) {
            v2f a01 = {0.f, 0.f}, a23 = {0.f, 0.f};
            float a4 = 0.f;
#pragma unroll
            for (int k = 0; k < 11; ++k) {
                unsigned int u = tile[i][w + k];
                float xv = __uint_as_float(u << 16);
                float yv = __uint_as_float(u & 0xffff0000u);
                float g  = gw.g[k];
                v2f g2 = {g, g};
                v2f xy = {xv, yv};
                a01 += g2 * xy;              // v_pk_fma_f32
                a23 += g2 * (xy * xy);       // v_pk_mul + v_pk_fma
                a4  += g * (xv * yv);
            }
            ring01[i%11] = a01; ring23[i%11] = a23; ring4[i%11] = a4;

            if (i >= 10) {
                const int j = i - 10;        // output row h0+j
                v2f o01 = {0.f, 0.f}, o23 = {0.f, 0.f};
                float o4 = 0.f;
#pragma unroll
                for (int k = 0; k < 11; ++k) {
                    float g = gw.g[k];
                    v2f g2 = {g, g};
                    o01 += g2 * ring01[(j + k) % 11];
                    o23 += g2 * ring23[(j + k) % 11];
                    o4  += g  * ring4 [(j + k) % 11];
                }
                size_t oi = outbase + (size_t)(h0 + j) * WW;
                ushort4 u4;
                u4.x = f2bf(o01.x); u4.y = f2bf(o01.y);
                u4.z = f2bf(o23.x); u4.w = f2bf(o23.y);
                B4[oi] = u4;
                B1[oi] = f2bf(o4);
            }
        }
    }
}

// ---------------- Pass B: D-conv + SSIM; flattened plane, uniform-branch edges ----
// block 256 (lane -> point p = h*160+w, fully coalesced); grid (100, 5, 4)
__global__ __launch_bounds__(256, 4) void k_dssim(
    const ushort4* __restrict__ B4, const unsigned short* __restrict__ B1,
    double* __restrict__ accum, Gw gw)
{
    const int tid = threadIdx.x;
    const int p   = blockIdx.x * 256 + tid;   // 0..25599
    const int d0  = blockIdx.y * RUN_D;       // 0,32,64,96,128
    const int n   = blockIdx.z;
    const size_t base = (size_t)n * VOL + p;

    v2f ring01[11], ring23[11];
    float ring4[11];
    float lsum = 0.f;

    // raw prefetch registers (data for current iteration i)
    ushort4 c4 = make_ushort4(0,0,0,0);
    unsigned short c1 = 0;
    {   // init for i=0 (dd = d0-5)
        if (d0 != 0) {
            size_t idx = base + (size_t)(d0 - 5) * PLANE;
            c4 = B4[idx]; c1 = B1[idx];
        }
    }

#pragma unroll
    for (int i = 0; i < RUN_D + 10; ++i) {
        // commit current slice into ring
        ring01[i%11] = (v2f){ bf2f(c4.x), bf2f(c4.y) };
        ring23[i%11] = (v2f){ bf2f(c4.z), bf2f(c4.w) };
        ring4 [i%11] = bf2f(c1);

        // prefetch slice for i+1 (block-uniform validity -> scalar branch)
        if (i + 1 < RUN_D + 10) {
            const int dd = d0 - 5 + i + 1;    // compile-time per unrolled i
            bool okNext = true;
            if (i + 1 < 5)   okNext = (d0 != 0);           // dd<0 only for seg 0
            if (i + 1 >= 37) okNext = (d0 != 128);         // dd>159 only for seg 4
            c4 = make_ushort4(0,0,0,0); c1 = 0;
            if (okNext) {
                size_t idx = base + (size_t)dd * PLANE;
                c4 = B4[idx]; c1 = B1[idx];
            }
        }

        if (i >= 10) {
            const int j = i - 10;
            v2f o01 = {0.f, 0.f}, o23 = {0.f, 0.f};
            float o4 = 0.f;
#pragma unroll
            for (int k = 0; k < 11; ++k) {
                float g = gw.g[k];
                v2f g2 = {g, g};
                o01 += g2 * ring01[(j + k) % 11];
                o23 += g2 * ring23[(j + k) % 11];
                o4  += g  * ring4 [(j + k) % 11];
            }
            float mu1 = o01.x, mu2 = o01.y;
            float e11 = o23.x, e22 = o23.y, e12 = o4;
            float m11 = mu1 * mu2;
            float num = (2.f * m11 + C1f) * (2.f * (e12 - m11) + C2f);
            float den = (mu1 * mu1 + mu2 * mu2 + C1f) *
                        ((e11 - mu1 * mu1) + (e22 - mu2 * mu2) + C2f);
            lsum += num / den;
        }
    }

    // 4-wave block reduce, one atomic
    __shared__ float wsum[4];
    const int lane = tid & 63, wi = tid >> 6;
#pragma unroll
    for (int off = 32; off > 0; off >>= 1)
        lsum += __shfl_down(lsum, off, 64);
    if (lane == 0) wsum[wi] = lsum;
    __syncthreads();
    if (tid == 0)
        atomicAdd(accum, (double)(wsum[0] + wsum[1] + wsum[2] + wsum[3]));
}

__global__ void k_final(const double* __restrict__ accum, float* __restrict__ out)
{
    out[0] = (float)(1.0 - accum[0] / ((double)NBATCH * (double)VOL));
}

extern "C" void kernel_launch(void* const* d_in, const int* in_sizes, int n_in,
                              void* d_out, int out_size, void* d_ws, size_t ws_size,
                              hipStream_t stream)
{
    const float* img1 = (const float*)d_in[0];
    const float* img2 = (const float*)d_in[1];
    float* out = (float*)d_out;

    char* ws = (char*)d_ws;
    ushort4* B4 = (ushort4*)ws;                                   // 4*VOL*8B  = 131.07 MB
    unsigned short* B1 = (unsigned short*)(ws + (size_t)NBATCH * VOL * 8);  // 32.77 MB
    double* accum = (double*)(ws + (size_t)NBATCH * VOL * 10);    // total 163.84 MB + 8

    Gw gw;
    {
        double gd[11], s = 0.0;
        for (int i = 0; i < 11; ++i) {
            double t = (double)(i - 5);
            gd[i] = exp(-(t * t) / (2.0 * 1.5 * 1.5));
            s += gd[i];
        }
        for (int i = 0; i < 11; ++i) gw.g[i] = (float)(gd[i] / s);
    }

    hipMemsetAsync(accum, 0, sizeof(double), stream);

    k_wh   <<<dim3(160 / RUN_H, 160, NBATCH), 192, 0, stream>>>(img1, img2, B4, B1, gw);
    k_dssim<<<dim3(PLANE / 256, 160 / RUN_D, NBATCH), 256, 0, stream>>>(B4, B1, accum, gw);
    k_final<<<1, 1, 0, stream>>>(accum, out);
}